// Round 1
// baseline (350.738 us; speedup 1.0000x reference)
//
#include <hip/hip_runtime.h>

// out[b,f] = -(sum_w x[b,w,f] * W[f,w] + bias[f])
// B=512, W_SIZE=5, F=25000.  F/4 = 6250 -> float4 everywhere.
//
// BPT=1 max-occupancy variant: each thread handles ONE (b, f-quad) pair.
// Per-thread live state ~55 VGPR (5 x-vectors, 20 W scalars, acc, addrs);
// __launch_bounds__(256, 8) pins VGPR<=64 -> 8 waves/SIMD = 32 waves/CU
// (vs ~4 waves/SIMD at BPT=4 with ~20 live x-vectors).
// Grid (25, 512) = 12800 blocks = 50 blocks/CU -> ~1% tail quantization.
// W/bias refetched 4x more often than BPT=4 but stays L2-resident
// (~300 MB L2 reads ~ 9 us at 34 TB/s, overlapped; NT x-loads bypass L2
// so L2 is free for W).

#define B_DIM 512
#define W_SIZE 5
#define F_DIM 25000
#define F4 (F_DIM / 4)   // 6250

typedef float v4f __attribute__((ext_vector_type(4)));

__global__ __launch_bounds__(256, 8) void ocsvm_kernel(
    const float* __restrict__ x,     // [B, W_SIZE, F]
    const float* __restrict__ W,     // [F, W_SIZE]
    const float* __restrict__ bias,  // [F]
    float* __restrict__ out)         // [B, F]
{
    const int f4 = blockIdx.x * blockDim.x + threadIdx.x;  // f-quad index
    if (f4 >= F4) return;
    const int f = f4 * 4;
    const int b = blockIdx.y;

    const float* xrow = x + (size_t)b * (W_SIZE * F_DIM) + f;

    // Issue all 5 streaming x loads up front (read-once -> nontemporal).
    v4f xv[W_SIZE];
#pragma unroll
    for (int w = 0; w < W_SIZE; ++w)
        xv[w] = __builtin_nontemporal_load(
            reinterpret_cast<const v4f*>(xrow + (size_t)w * F_DIM));

    // W rows for f..f+3: 20 contiguous floats, 16B-aligned. L2-resident
    // (reused by all 512 b-blocks) -> normal cached loads.
    const float* wp = W + (size_t)f * W_SIZE;
    v4f w0 = *reinterpret_cast<const v4f*>(wp + 0);
    v4f w1 = *reinterpret_cast<const v4f*>(wp + 4);
    v4f w2 = *reinterpret_cast<const v4f*>(wp + 8);
    v4f w3 = *reinterpret_cast<const v4f*>(wp + 12);
    v4f w4 = *reinterpret_cast<const v4f*>(wp + 16);
    v4f bias4 = *reinterpret_cast<const v4f*>(bias + f);

    // per-f weight vectors (registers; indexed only by unrolled constants)
    const float wf0[5] = {w0.x, w0.y, w0.z, w0.w, w1.x};
    const float wf1[5] = {w1.y, w1.z, w1.w, w2.x, w2.y};
    const float wf2[5] = {w2.z, w2.w, w3.x, w3.y, w3.z};
    const float wf3[5] = {w3.w, w4.x, w4.y, w4.z, w4.w};

    v4f acc = bias4;
#pragma unroll
    for (int w = 0; w < W_SIZE; ++w) {
        acc.x = fmaf(xv[w].x, wf0[w], acc.x);
        acc.y = fmaf(xv[w].y, wf1[w], acc.y);
        acc.z = fmaf(xv[w].z, wf2[w], acc.z);
        acc.w = fmaf(xv[w].w, wf3[w], acc.w);
    }

    __builtin_nontemporal_store(-acc,
        reinterpret_cast<v4f*>(out + (size_t)b * F_DIM + f));
}

extern "C" void kernel_launch(void* const* d_in, const int* in_sizes, int n_in,
                              void* d_out, int out_size, void* d_ws, size_t ws_size,
                              hipStream_t stream) {
    const float* x    = (const float*)d_in[0];
    const float* W    = (const float*)d_in[1];
    const float* bias = (const float*)d_in[2];
    float* out = (float*)d_out;

    dim3 block(256);
    dim3 grid((F4 + 255) / 256, B_DIM);  // (25, 512)
    ocsvm_kernel<<<grid, block, 0, stream>>>(x, W, bias, out);
}

// Round 2
// 347.187 us; speedup vs baseline: 1.0102x; 1.0102x over previous
//
#include <hip/hip_runtime.h>

// out[b,f] = -(sum_w x[b,w,f] * W[f,w] + bias[f])
// B=512, W_SIZE=5, F=25000.  F/4 = 6250 -> float4 everywhere.
//
// BPT=8 @ 64-thread blocks:
//  - W/bias amortization halves vs BPT=4 (each thread's 96 B of W+bias now
//    covers 640 B of x).  BPT=1 A/B showed this term is real (~+10 us at 4x).
//  - 64-thread (1-wave) blocks fix the tail-quantization objection to BPT=8:
//    grid (98, 64) = 6272 blocks = 24.5/CU -> ~2% imbalance (vs 12% at
//    256-thread/1600-block BPT=8, ~4% at BPT=4/3200-block).
//  - x loads nontemporal (read-once, bypass L2); out stores nontemporal.
//  - No min-waves cap: BPT=1 proved occupancy is NOT the limiter; let the
//    compiler keep as many of the 40 x-vectors in flight as it likes.

#define B_DIM 512
#define W_SIZE 5
#define F_DIM 25000
#define F4 (F_DIM / 4)   // 6250
#define BPT 8            // b values per thread

typedef float v4f __attribute__((ext_vector_type(4)));

__global__ __launch_bounds__(64) void ocsvm_kernel(
    const float* __restrict__ x,     // [B, W_SIZE, F]
    const float* __restrict__ W,     // [F, W_SIZE]
    const float* __restrict__ bias,  // [F]
    float* __restrict__ out)         // [B, F]
{
    const int f4 = blockIdx.x * blockDim.x + threadIdx.x;  // f-quad index
    if (f4 >= F4) return;
    const int f  = f4 * 4;
    const int b0 = blockIdx.y * BPT;

    // bias for 4 consecutive f (cache-resident, reused across all b)
    v4f bias4 = *reinterpret_cast<const v4f*>(bias + f);

    // W rows for f..f+3: 20 contiguous floats, 16B-aligned
    const float* wp = W + (size_t)f * W_SIZE;
    v4f w0 = *reinterpret_cast<const v4f*>(wp + 0);
    v4f w1 = *reinterpret_cast<const v4f*>(wp + 4);
    v4f w2 = *reinterpret_cast<const v4f*>(wp + 8);
    v4f w3 = *reinterpret_cast<const v4f*>(wp + 12);
    v4f w4 = *reinterpret_cast<const v4f*>(wp + 16);

    // per-f weight vectors (registers; indexed only by unrolled constants)
    const float wf0[5] = {w0.x, w0.y, w0.z, w0.w, w1.x};
    const float wf1[5] = {w1.y, w1.z, w1.w, w2.x, w2.y};
    const float wf2[5] = {w2.z, w2.w, w3.x, w3.y, w3.z};
    const float wf3[5] = {w3.w, w4.x, w4.y, w4.z, w4.w};

    const float* xb = x + (size_t)b0 * (W_SIZE * F_DIM) + f;
    float*       op = out + (size_t)b0 * F_DIM + f;

#pragma unroll
    for (int bb = 0; bb < BPT; ++bb) {
        const float* xrow = xb + (size_t)bb * (W_SIZE * F_DIM);
        v4f xv[W_SIZE];
#pragma unroll
        for (int w = 0; w < W_SIZE; ++w)
            xv[w] = __builtin_nontemporal_load(
                reinterpret_cast<const v4f*>(xrow + (size_t)w * F_DIM));

        v4f acc = bias4;
#pragma unroll
        for (int w = 0; w < W_SIZE; ++w) {
            acc.x = fmaf(xv[w].x, wf0[w], acc.x);
            acc.y = fmaf(xv[w].y, wf1[w], acc.y);
            acc.z = fmaf(xv[w].z, wf2[w], acc.z);
            acc.w = fmaf(xv[w].w, wf3[w], acc.w);
        }
        __builtin_nontemporal_store(-acc,
            reinterpret_cast<v4f*>(op + (size_t)bb * F_DIM));
    }
}

extern "C" void kernel_launch(void* const* d_in, const int* in_sizes, int n_in,
                              void* d_out, int out_size, void* d_ws, size_t ws_size,
                              hipStream_t stream) {
    const float* x    = (const float*)d_in[0];
    const float* W    = (const float*)d_in[1];
    const float* bias = (const float*)d_in[2];
    float* out = (float*)d_out;

    dim3 block(64);
    dim3 grid((F4 + 63) / 64, B_DIM / BPT);  // (98, 64)
    ocsvm_kernel<<<grid, block, 0, stream>>>(x, W, bias, out);
}

// Round 3
// 340.325 us; speedup vs baseline: 1.0306x; 1.0202x over previous
//
#include <hip/hip_runtime.h>

// out[b,f] = -(sum_w x[b,w,f] * W[f,w] + bias[f])
// B=512, W_SIZE=5, F=25000.  F/4 = 6250 exactly -> float4 everywhere.
//
// BPT=4 @ 256-thread blocks: the measured optimum of the BPT A/B matrix
//   BPT=1: 350.7 us (+9.6; 4x W/bias L2 refetch, matches arithmetic)
//   BPT=4: 341.1 / 337.9 us  <-- this kernel
//   BPT=8: 347.2 us (+6.1; 40 live x-vectors -> VGPR pressure/pipeline cost)
// Kernel itself is ~50 us vs a 47 us compulsory-traffic floor (307.2 MB at
// the 6.6 TB/s the harness's own fills achieve); the remaining ~290 us of
// the score is fixed harness reset work.  No byte-reduction lever exists:
// x is read-once (NT loads bypass L2), out write-once (NT stores).

#define B_DIM 512
#define W_SIZE 5
#define F_DIM 25000
#define F4 (F_DIM / 4)   // 6250
#define BPT 4            // b values per thread

typedef float v4f __attribute__((ext_vector_type(4)));

__global__ __launch_bounds__(256) void ocsvm_kernel(
    const float* __restrict__ x,     // [B, W_SIZE, F]
    const float* __restrict__ W,     // [F, W_SIZE]
    const float* __restrict__ bias,  // [F]
    float* __restrict__ out)         // [B, F]
{
    const int f4 = blockIdx.x * blockDim.x + threadIdx.x;  // f-quad index
    if (f4 >= F4) return;
    const int f  = f4 * 4;
    const int b0 = blockIdx.y * BPT;

    // bias for 4 consecutive f (L2-resident, reused across all b)
    v4f bias4 = *reinterpret_cast<const v4f*>(bias + f);

    // W rows for f..f+3: 20 contiguous floats, 16B-aligned
    const float* wp = W + (size_t)f * W_SIZE;
    v4f w0 = *reinterpret_cast<const v4f*>(wp + 0);
    v4f w1 = *reinterpret_cast<const v4f*>(wp + 4);
    v4f w2 = *reinterpret_cast<const v4f*>(wp + 8);
    v4f w3 = *reinterpret_cast<const v4f*>(wp + 12);
    v4f w4 = *reinterpret_cast<const v4f*>(wp + 16);

    // per-f weight vectors (registers; indexed only by unrolled constants)
    const float wf0[5] = {w0.x, w0.y, w0.z, w0.w, w1.x};
    const float wf1[5] = {w1.y, w1.z, w1.w, w2.x, w2.y};
    const float wf2[5] = {w2.z, w2.w, w3.x, w3.y, w3.z};
    const float wf3[5] = {w3.w, w4.x, w4.y, w4.z, w4.w};

    const float* xb = x + (size_t)b0 * (W_SIZE * F_DIM) + f;
    float*       op = out + (size_t)b0 * F_DIM + f;

#pragma unroll
    for (int bb = 0; bb < BPT; ++bb) {
        const float* xrow = xb + (size_t)bb * (W_SIZE * F_DIM);
        v4f xv[W_SIZE];
#pragma unroll
        for (int w = 0; w < W_SIZE; ++w)
            xv[w] = __builtin_nontemporal_load(
                reinterpret_cast<const v4f*>(xrow + (size_t)w * F_DIM));

        v4f acc = bias4;
#pragma unroll
        for (int w = 0; w < W_SIZE; ++w) {
            acc.x = fmaf(xv[w].x, wf0[w], acc.x);
            acc.y = fmaf(xv[w].y, wf1[w], acc.y);
            acc.z = fmaf(xv[w].z, wf2[w], acc.z);
            acc.w = fmaf(xv[w].w, wf3[w], acc.w);
        }
        __builtin_nontemporal_store(-acc,
            reinterpret_cast<v4f*>(op + (size_t)bb * F_DIM));
    }
}

extern "C" void kernel_launch(void* const* d_in, const int* in_sizes, int n_in,
                              void* d_out, int out_size, void* d_ws, size_t ws_size,
                              hipStream_t stream) {
    const float* x    = (const float*)d_in[0];
    const float* W    = (const float*)d_in[1];
    const float* bias = (const float*)d_in[2];
    float* out = (float*)d_out;

    dim3 block(256);
    dim3 grid((F4 + 255) / 256, B_DIM / BPT);  // (25, 128)
    ocsvm_kernel<<<grid, block, 0, stream>>>(x, W, bias, out);
}